// Round 1
// baseline (237.623 us; speedup 1.0000x reference)
//
#include <hip/hip_runtime.h>
#include <hip/hip_bf16.h>

#define D_MODEL 1024
#define NHEAD 16
#define DH 64
#define BSZ 2
#define SEQ 2048
#define MROWS (BSZ*SEQ)

typedef __attribute__((ext_vector_type(4))) float f32x4;
typedef __attribute__((ext_vector_type(8))) __bf16 bf16x8;
typedef __attribute__((ext_vector_type(8))) unsigned short u16x8;

__device__ __forceinline__ float b2f(unsigned short u) {
    union { unsigned int i; float f; } v; v.i = ((unsigned int)u) << 16; return v.f;
}
__device__ __forceinline__ unsigned short f2b(float f) {
    union { float f; unsigned int i; } v; v.f = f;
    unsigned int u = v.i;
    u += 0x7fffu + ((u >> 16) & 1u);
    return (unsigned short)(u >> 16);
}

#define GLDS16(gptr, lptr) \
    __builtin_amdgcn_global_load_lds((__attribute__((address_space(1))) void*)(gptr), \
                                     (__attribute__((address_space(3))) void*)(lptr), 16, 0, 0)

// ---------------- f32 -> bf16 convert ----------------
__global__ __launch_bounds__(256) void cvt_f32_bf16(const float* __restrict__ src,
                                                    unsigned short* __restrict__ dst, int n4) {
    int i = blockIdx.x * 256 + threadIdx.x;
    int stride = gridDim.x * 256;
    for (; i < n4; i += stride) {
        float4 v = ((const float4*)src)[i];
        ushort4 o;
        o.x = f2b(v.x); o.y = f2b(v.y); o.z = f2b(v.z); o.w = f2b(v.w);
        ((ushort4*)dst)[i] = o;
    }
}

// ---------------- QKV GEMM: out = x @ W^T + b, head-split bf16 output ----------------
__global__ __launch_bounds__(256) void gemm_qkv(
    const unsigned short* __restrict__ X,
    const unsigned short* __restrict__ Wq, const unsigned short* __restrict__ Wk,
    const unsigned short* __restrict__ Wv,
    const float* __restrict__ bq, const float* __restrict__ bk, const float* __restrict__ bv,
    unsigned short* __restrict__ Qo, unsigned short* __restrict__ Ko, unsigned short* __restrict__ Vo)
{
    __shared__ unsigned short lsA[128*32];
    __shared__ unsigned short lsB[128*32];
    const int tid = threadIdx.x;
    const int z = blockIdx.z;
    const unsigned short* W = (z==0) ? Wq : (z==1) ? Wk : Wv;
    const float* bias = (z==0) ? bq : (z==1) ? bk : bv;
    unsigned short* Out = (z==0) ? Qo : (z==1) ? Ko : Vo;
    const int tM = blockIdx.y * 128;
    const int tN = blockIdx.x * 128;
    const int w = tid >> 6, lane = tid & 63;
    const int wr = w >> 1, wc = w & 1;
    const int lr = lane & 15, lk = lane >> 4;
    const f32x4 fz = {0.f, 0.f, 0.f, 0.f};
    f32x4 acc[4][4];
    #pragma unroll
    for (int m = 0; m < 4; m++)
        #pragma unroll
        for (int n = 0; n < 4; n++) acc[m][n] = fz;

    const int e0 = tid, e1 = 256 + tid;
    const int r0 = e0 >> 2, c0 = ((e0 & 3) ^ (r0 & 3)) * 8;
    const int r1 = e1 >> 2, c1 = ((e1 & 3) ^ (r1 & 3)) * 8;

    for (int k0 = 0; k0 < D_MODEL; k0 += 32) {
        GLDS16(X + (size_t)(tM + r0) * D_MODEL + k0 + c0, &lsA[e0 * 8]);
        GLDS16(X + (size_t)(tM + r1) * D_MODEL + k0 + c1, &lsA[e1 * 8]);
        GLDS16(W + (size_t)(tN + r0) * D_MODEL + k0 + c0, &lsB[e0 * 8]);
        GLDS16(W + (size_t)(tN + r1) * D_MODEL + k0 + c1, &lsB[e1 * 8]);
        __syncthreads();
        bf16x8 af[4], bfr[4];
        #pragma unroll
        for (int m = 0; m < 4; m++) {
            int row = wr*64 + m*16 + lr;
            af[m] = *(const bf16x8*)&lsA[row*32 + ((lk ^ (row & 3)) * 8)];
        }
        #pragma unroll
        for (int n = 0; n < 4; n++) {
            int row = wc*64 + n*16 + lr;
            bfr[n] = *(const bf16x8*)&lsB[row*32 + ((lk ^ (row & 3)) * 8)];
        }
        #pragma unroll
        for (int m = 0; m < 4; m++)
            #pragma unroll
            for (int n = 0; n < 4; n++)
                acc[m][n] = __builtin_amdgcn_mfma_f32_16x16x32_bf16(af[m], bfr[n], acc[m][n], 0, 0, 0);
        __syncthreads();
    }
    #pragma unroll
    for (int m = 0; m < 4; m++) {
        int ibase = tM + wr*64 + m*16 + lk*4;
        #pragma unroll
        for (int n = 0; n < 4; n++) {
            int j = tN + wc*64 + n*16 + lr;
            float bj = bias[j];
            int h = j >> 6, d = j & 63;
            #pragma unroll
            for (int r = 0; r < 4; r++) {
                int row = ibase + r;
                int b = row >> 11, s = row & 2047;
                Out[((size_t)(b*NHEAD + h) * SEQ + s) * DH + d] = f2b(acc[m][n][r] + bj);
            }
        }
    }
}

// ---------------- Output GEMM: out = A @ W^T + b, f32 output ----------------
__global__ __launch_bounds__(256) void gemm_out(
    const unsigned short* __restrict__ X, const unsigned short* __restrict__ W,
    const float* __restrict__ bias, float* __restrict__ Out)
{
    __shared__ unsigned short lsA[128*32];
    __shared__ unsigned short lsB[128*32];
    const int tid = threadIdx.x;
    const int tM = blockIdx.y * 128;
    const int tN = blockIdx.x * 128;
    const int w = tid >> 6, lane = tid & 63;
    const int wr = w >> 1, wc = w & 1;
    const int lr = lane & 15, lk = lane >> 4;
    const f32x4 fz = {0.f, 0.f, 0.f, 0.f};
    f32x4 acc[4][4];
    #pragma unroll
    for (int m = 0; m < 4; m++)
        #pragma unroll
        for (int n = 0; n < 4; n++) acc[m][n] = fz;

    const int e0 = tid, e1 = 256 + tid;
    const int r0 = e0 >> 2, c0 = ((e0 & 3) ^ (r0 & 3)) * 8;
    const int r1 = e1 >> 2, c1 = ((e1 & 3) ^ (r1 & 3)) * 8;

    for (int k0 = 0; k0 < D_MODEL; k0 += 32) {
        GLDS16(X + (size_t)(tM + r0) * D_MODEL + k0 + c0, &lsA[e0 * 8]);
        GLDS16(X + (size_t)(tM + r1) * D_MODEL + k0 + c1, &lsA[e1 * 8]);
        GLDS16(W + (size_t)(tN + r0) * D_MODEL + k0 + c0, &lsB[e0 * 8]);
        GLDS16(W + (size_t)(tN + r1) * D_MODEL + k0 + c1, &lsB[e1 * 8]);
        __syncthreads();
        bf16x8 af[4], bfr[4];
        #pragma unroll
        for (int m = 0; m < 4; m++) {
            int row = wr*64 + m*16 + lr;
            af[m] = *(const bf16x8*)&lsA[row*32 + ((lk ^ (row & 3)) * 8)];
        }
        #pragma unroll
        for (int n = 0; n < 4; n++) {
            int row = wc*64 + n*16 + lr;
            bfr[n] = *(const bf16x8*)&lsB[row*32 + ((lk ^ (row & 3)) * 8)];
        }
        #pragma unroll
        for (int m = 0; m < 4; m++)
            #pragma unroll
            for (int n = 0; n < 4; n++)
                acc[m][n] = __builtin_amdgcn_mfma_f32_16x16x32_bf16(af[m], bfr[n], acc[m][n], 0, 0, 0);
        __syncthreads();
    }
    #pragma unroll
    for (int m = 0; m < 4; m++) {
        int ibase = tM + wr*64 + m*16 + lk*4;
        #pragma unroll
        for (int n = 0; n < 4; n++) {
            int j = tN + wc*64 + n*16 + lr;
            float bj = bias[j];
            #pragma unroll
            for (int r = 0; r < 4; r++)
                Out[(size_t)(ibase + r) * D_MODEL + j] = acc[m][n][r] + bj;
        }
    }
}

// ---------------- V transpose: [bh][s][d] -> [bh][d][s] ----------------
__global__ __launch_bounds__(256) void vtrans(const unsigned short* __restrict__ V,
                                              unsigned short* __restrict__ Vt) {
    __shared__ unsigned short t[64][80];
    const int bh = blockIdx.y;
    const int s0 = blockIdx.x * 64;
    const int tid = threadIdx.x;
    #pragma unroll
    for (int i = 0; i < 2; i++) {
        int e = i*256 + tid;
        int r = e >> 3, c = e & 7;
        u16x8 v = *(const u16x8*)&V[((size_t)bh * SEQ + s0 + r) * DH + c*8];
        *(u16x8*)&t[r][c*8] = v;
    }
    __syncthreads();
    #pragma unroll
    for (int i = 0; i < 2; i++) {
        int e = i*256 + tid;
        int d = e >> 3, c = e & 7;
        u16x8 o;
        #pragma unroll
        for (int j = 0; j < 8; j++) o[j] = t[c*8 + j][d];
        *(u16x8*)&Vt[((size_t)bh * DH + d) * SEQ + s0 + c*8] = o;
    }
}

// ---------------- qer[b,h,l] = dot(Q[b,h,l,:], Er[l,:]) ----------------
__global__ __launch_bounds__(256) void qer_k(const unsigned short* __restrict__ Q,
                                             const float* __restrict__ Er,
                                             float* __restrict__ qer) {
    int gw = blockIdx.x * 4 + (threadIdx.x >> 6);
    int lane = threadIdx.x & 63;
    int l = gw & (SEQ - 1);
    float p = b2f(Q[(size_t)gw * DH + lane]) * Er[l * DH + lane];
    #pragma unroll
    for (int m = 32; m >= 1; m >>= 1) p += __shfl_xor(p, m, 64);
    if (lane == 0) qer[gw] = p;
}

// ---------------- flash attention with relative bias ----------------
__global__ __launch_bounds__(256) void attn_k(
    const unsigned short* __restrict__ Q, const unsigned short* __restrict__ Kg,
    const unsigned short* __restrict__ Vt, const float* __restrict__ qer,
    unsigned short* __restrict__ Om)
{
    __shared__ unsigned short lsK[64*64];
    __shared__ unsigned short lsV[64*64];
    __shared__ unsigned short lsP[4][16*72];
    const int qt = blockIdx.x, bh = blockIdx.y;
    const int b = bh >> 4, h = bh & 15;
    const int tid = threadIdx.x;
    const int w = tid >> 6, lane = tid & 63;
    const int lr = lane & 15, lk = lane >> 4;
    const f32x4 fz = {0.f, 0.f, 0.f, 0.f};

    const unsigned short* Qrow = Q + ((size_t)bh * SEQ + qt*64 + w*16 + lr) * DH;
    bf16x8 aq0 = *(const bf16x8*)&Qrow[lk*8];
    bf16x8 aq1 = *(const bf16x8*)&Qrow[32 + lk*8];

    f32x4 o[4];
    #pragma unroll
    for (int nt = 0; nt < 4; nt++) o[nt] = fz;
    float mrow[4], lsum[4];
    #pragma unroll
    for (int r = 0; r < 4; r++) { mrow[r] = -3.0e38f; lsum[r] = 0.0f; }
    const float SCL = 0.125f * 1.44269504088896f;  // 1/sqrt(64) * log2(e)

    for (int kt = 0; kt <= qt; kt++) {
        #pragma unroll
        for (int i = 0; i < 2; i++) {
            int e = i*256 + tid;
            int r = e >> 3, c = ((e & 7) ^ (r & 7)) * 8;
            GLDS16(Kg + ((size_t)bh * SEQ + kt*64 + r) * DH + c, &lsK[e * 8]);
            GLDS16(Vt + ((size_t)bh * DH + r) * SEQ + kt*64 + c, &lsV[e * 8]);
        }
        __syncthreads();
        // QK^T
        f32x4 sc[4];
        #pragma unroll
        for (int nt = 0; nt < 4; nt++) {
            int row = nt*16 + lr;
            bf16x8 b0 = *(const bf16x8*)&lsK[row*64 + ((lk ^ (row & 7)) * 8)];
            bf16x8 b1 = *(const bf16x8*)&lsK[row*64 + (((4 + lk) ^ (row & 7)) * 8)];
            f32x4 zacc = fz;
            zacc = __builtin_amdgcn_mfma_f32_16x16x32_bf16(aq0, b0, zacc, 0, 0, 0);
            zacc = __builtin_amdgcn_mfma_f32_16x16x32_bf16(aq1, b1, zacc, 0, 0, 0);
            sc[nt] = zacc;
        }
        // bias + scale + causal mask
        float st[4][4];
        #pragma unroll
        for (int nt = 0; nt < 4; nt++) {
            int mcol = kt*64 + nt*16 + lr;
            float bias = 0.0f;
            if (mcol & 1) bias = qer[(size_t)bh * SEQ + ((SEQ - 1 + mcol) >> 1)];
            #pragma unroll
            for (int r = 0; r < 4; r++)
                st[nt][r] = (sc[nt][r] + bias) * SCL;
        }
        if (kt == qt) {
            #pragma unroll
            for (int nt = 0; nt < 4; nt++) {
                int mcol = kt*64 + nt*16 + lr;
                #pragma unroll
                for (int r = 0; r < 4; r++) {
                    int rowg = qt*64 + w*16 + lk*4 + r;
                    if (mcol > rowg) st[nt][r] = -3.0e38f;
                }
            }
        }
        // online softmax (per 16-lane group, 4 rows per lane)
        #pragma unroll
        for (int r = 0; r < 4; r++) {
            float pm = fmaxf(fmaxf(st[0][r], st[1][r]), fmaxf(st[2][r], st[3][r]));
            pm = fmaxf(pm, __shfl_xor(pm, 1, 64));
            pm = fmaxf(pm, __shfl_xor(pm, 2, 64));
            pm = fmaxf(pm, __shfl_xor(pm, 4, 64));
            pm = fmaxf(pm, __shfl_xor(pm, 8, 64));
            float mnew = fmaxf(mrow[r], pm);
            float scale = exp2f(mrow[r] - mnew);
            float rs = 0.0f;
            #pragma unroll
            for (int nt = 0; nt < 4; nt++) {
                float p = exp2f(st[nt][r] - mnew);
                st[nt][r] = p;
                rs += p;
            }
            rs += __shfl_xor(rs, 1, 64);
            rs += __shfl_xor(rs, 2, 64);
            rs += __shfl_xor(rs, 4, 64);
            rs += __shfl_xor(rs, 8, 64);
            lsum[r] = lsum[r] * scale + rs;
            mrow[r] = mnew;
            #pragma unroll
            for (int nt = 0; nt < 4; nt++) o[nt][r] *= scale;
        }
        // P -> LDS (bf16), per-wave buffer
        #pragma unroll
        for (int nt = 0; nt < 4; nt++)
            #pragma unroll
            for (int r = 0; r < 4; r++)
                lsP[w][(lk*4 + r)*72 + nt*16 + lr] = f2b(st[nt][r]);
        bf16x8 pa0 = *(const bf16x8*)&lsP[w][lr*72 + lk*8];
        bf16x8 pa1 = *(const bf16x8*)&lsP[w][lr*72 + 32 + lk*8];
        // PV
        #pragma unroll
        for (int nt = 0; nt < 4; nt++) {
            int row = nt*16 + lr;
            bf16x8 v0 = *(const bf16x8*)&lsV[row*64 + ((lk ^ (row & 7)) * 8)];
            bf16x8 v1 = *(const bf16x8*)&lsV[row*64 + (((4 + lk) ^ (row & 7)) * 8)];
            o[nt] = __builtin_amdgcn_mfma_f32_16x16x32_bf16(pa0, v0, o[nt], 0, 0, 0);
            o[nt] = __builtin_amdgcn_mfma_f32_16x16x32_bf16(pa1, v1, o[nt], 0, 0, 0);
        }
        __syncthreads();
    }
    // epilogue: merged-head layout [b, s, h*64+d], bf16
    #pragma unroll
    for (int nt = 0; nt < 4; nt++) {
        int dcol = h*64 + nt*16 + lr;
        #pragma unroll
        for (int r = 0; r < 4; r++) {
            int srow = qt*64 + w*16 + lk*4 + r;
            float val = o[nt][r] / lsum[r];
            Om[((size_t)(b * SEQ + srow)) * D_MODEL + dcol] = f2b(val);
        }
    }
}

extern "C" void kernel_launch(void* const* d_in, const int* in_sizes, int n_in,
                              void* d_out, int out_size, void* d_ws, size_t ws_size,
                              hipStream_t stream) {
    const float* x  = (const float*)d_in[0];
    const float* Wq = (const float*)d_in[1];
    const float* bq = (const float*)d_in[2];
    const float* Wk = (const float*)d_in[3];
    const float* bk = (const float*)d_in[4];
    const float* Wv = (const float*)d_in[5];
    const float* bv = (const float*)d_in[6];
    const float* Wo = (const float*)d_in[7];
    const float* bo = (const float*)d_in[8];
    const float* Er = (const float*)d_in[9];

    char* ws = (char*)d_ws;
    unsigned short* xb  = (unsigned short*)(ws);                      // 8 MB; reused as attn out
    unsigned short* Wqb = (unsigned short*)(ws + 8388608);            // 2 MB
    unsigned short* Wkb = (unsigned short*)(ws + 8388608 + 2097152);
    unsigned short* Wvb = (unsigned short*)(ws + 8388608 + 2*2097152);
    unsigned short* Wob = (unsigned short*)(ws + 8388608 + 3*2097152);
    unsigned short* Qb  = (unsigned short*)(ws + 16777216);           // 8 MB
    unsigned short* Kb  = (unsigned short*)(ws + 16777216 + 8388608);
    unsigned short* Vb  = (unsigned short*)(ws + 16777216 + 2*8388608);
    unsigned short* Vtb = (unsigned short*)(ws + 16777216 + 3*8388608);
    float* qer          = (float*)(ws + 16777216 + 4*8388608);        // 256 KB

    cvt_f32_bf16<<<2048, 256, 0, stream>>>(x,  xb,  MROWS*D_MODEL/4);
    cvt_f32_bf16<<<1024, 256, 0, stream>>>(Wq, Wqb, D_MODEL*D_MODEL/4);
    cvt_f32_bf16<<<1024, 256, 0, stream>>>(Wk, Wkb, D_MODEL*D_MODEL/4);
    cvt_f32_bf16<<<1024, 256, 0, stream>>>(Wv, Wvb, D_MODEL*D_MODEL/4);
    cvt_f32_bf16<<<1024, 256, 0, stream>>>(Wo, Wob, D_MODEL*D_MODEL/4);

    gemm_qkv<<<dim3(8, 32, 3), 256, 0, stream>>>(xb, Wqb, Wkb, Wvb, bq, bk, bv, Qb, Kb, Vb);
    vtrans<<<dim3(32, 32), 256, 0, stream>>>(Vb, Vtb);
    qer_k<<<16384, 256, 0, stream>>>(Qb, Er, qer);
    attn_k<<<dim3(32, 32), 256, 0, stream>>>(Qb, Kb, Vtb, qer, xb);
    gemm_out<<<dim3(8, 32), 256, 0, stream>>>(xb, Wob, bo, (float*)d_out);
}

// Round 2
// 160.019 us; speedup vs baseline: 1.4850x; 1.4850x over previous
//
#include <hip/hip_runtime.h>
#include <hip/hip_bf16.h>

#define D_MODEL 1024
#define NHEAD 16
#define DH 64
#define BSZ 2
#define SEQ 2048
#define MROWS (BSZ*SEQ)

typedef __attribute__((ext_vector_type(4))) float f32x4;
typedef __attribute__((ext_vector_type(8))) __bf16 bf16x8;
typedef __attribute__((ext_vector_type(8))) unsigned short u16x8;

__device__ __forceinline__ float b2f(unsigned short u) {
    union { unsigned int i; float f; } v; v.i = ((unsigned int)u) << 16; return v.f;
}
__device__ __forceinline__ unsigned short f2b(float f) {
    union { float f; unsigned int i; } v; v.f = f;
    unsigned int u = v.i;
    u += 0x7fffu + ((u >> 16) & 1u);
    return (unsigned short)(u >> 16);
}

#define GLDS16(gptr, lptr) \
    __builtin_amdgcn_global_load_lds((__attribute__((address_space(1))) void*)(gptr), \
                                     (__attribute__((address_space(3))) void*)(lptr), 16, 0, 0)

// ---------------- f32 -> bf16 convert ----------------
__global__ __launch_bounds__(256) void cvt_f32_bf16(const float* __restrict__ src,
                                                    unsigned short* __restrict__ dst, int n4) {
    int i = blockIdx.x * 256 + threadIdx.x;
    int stride = gridDim.x * 256;
    for (; i < n4; i += stride) {
        float4 v = ((const float4*)src)[i];
        ushort4 o;
        o.x = f2b(v.x); o.y = f2b(v.y); o.z = f2b(v.z); o.w = f2b(v.w);
        ((ushort4*)dst)[i] = o;
    }
}

// ---------------- QKV GEMM: out = x @ W^T + b, head-split bf16 output ----------------
__global__ __launch_bounds__(256) void gemm_qkv(
    const unsigned short* __restrict__ X,
    const unsigned short* __restrict__ Wq, const unsigned short* __restrict__ Wk,
    const unsigned short* __restrict__ Wv,
    const float* __restrict__ bq, const float* __restrict__ bk, const float* __restrict__ bv,
    unsigned short* __restrict__ Qo, unsigned short* __restrict__ Ko, unsigned short* __restrict__ Vo)
{
    __shared__ unsigned short lsA[128*32];
    __shared__ unsigned short lsB[128*32];
    const int tid = threadIdx.x;
    const int z = blockIdx.z;
    const unsigned short* W = (z==0) ? Wq : (z==1) ? Wk : Wv;
    const float* bias = (z==0) ? bq : (z==1) ? bk : bv;
    unsigned short* Out = (z==0) ? Qo : (z==1) ? Ko : Vo;
    const int tM = blockIdx.y * 128;
    const int tN = blockIdx.x * 128;
    const int w = tid >> 6, lane = tid & 63;
    const int wr = w >> 1, wc = w & 1;
    const int lr = lane & 15, lk = lane >> 4;
    const f32x4 fz = {0.f, 0.f, 0.f, 0.f};
    f32x4 acc[4][4];
    #pragma unroll
    for (int m = 0; m < 4; m++)
        #pragma unroll
        for (int n = 0; n < 4; n++) acc[m][n] = fz;

    const int e0 = tid, e1 = 256 + tid;
    const int r0 = e0 >> 2, c0 = ((e0 & 3) ^ (r0 & 3)) * 8;
    const int r1 = e1 >> 2, c1 = ((e1 & 3) ^ (r1 & 3)) * 8;

    for (int k0 = 0; k0 < D_MODEL; k0 += 32) {
        GLDS16(X + (size_t)(tM + r0) * D_MODEL + k0 + c0, &lsA[e0 * 8]);
        GLDS16(X + (size_t)(tM + r1) * D_MODEL + k0 + c1, &lsA[e1 * 8]);
        GLDS16(W + (size_t)(tN + r0) * D_MODEL + k0 + c0, &lsB[e0 * 8]);
        GLDS16(W + (size_t)(tN + r1) * D_MODEL + k0 + c1, &lsB[e1 * 8]);
        __syncthreads();
        bf16x8 af[4], bfr[4];
        #pragma unroll
        for (int m = 0; m < 4; m++) {
            int row = wr*64 + m*16 + lr;
            af[m] = *(const bf16x8*)&lsA[row*32 + ((lk ^ (row & 3)) * 8)];
        }
        #pragma unroll
        for (int n = 0; n < 4; n++) {
            int row = wc*64 + n*16 + lr;
            bfr[n] = *(const bf16x8*)&lsB[row*32 + ((lk ^ (row & 3)) * 8)];
        }
        #pragma unroll
        for (int m = 0; m < 4; m++)
            #pragma unroll
            for (int n = 0; n < 4; n++)
                acc[m][n] = __builtin_amdgcn_mfma_f32_16x16x32_bf16(af[m], bfr[n], acc[m][n], 0, 0, 0);
        __syncthreads();
    }
    #pragma unroll
    for (int m = 0; m < 4; m++) {
        int ibase = tM + wr*64 + m*16 + lk*4;
        #pragma unroll
        for (int n = 0; n < 4; n++) {
            int j = tN + wc*64 + n*16 + lr;
            float bj = bias[j];
            int h = j >> 6, d = j & 63;
            #pragma unroll
            for (int r = 0; r < 4; r++) {
                int row = ibase + r;
                int b = row >> 11, s = row & 2047;
                Out[((size_t)(b*NHEAD + h) * SEQ + s) * DH + d] = f2b(acc[m][n][r] + bj);
            }
        }
    }
}

// ---------------- Output GEMM: out = A @ W^T + b, f32 output ----------------
__global__ __launch_bounds__(256) void gemm_out(
    const unsigned short* __restrict__ X, const unsigned short* __restrict__ W,
    const float* __restrict__ bias, float* __restrict__ Out)
{
    __shared__ unsigned short lsA[128*32];
    __shared__ unsigned short lsB[128*32];
    const int tid = threadIdx.x;
    const int tM = blockIdx.y * 128;
    const int tN = blockIdx.x * 128;
    const int w = tid >> 6, lane = tid & 63;
    const int wr = w >> 1, wc = w & 1;
    const int lr = lane & 15, lk = lane >> 4;
    const f32x4 fz = {0.f, 0.f, 0.f, 0.f};
    f32x4 acc[4][4];
    #pragma unroll
    for (int m = 0; m < 4; m++)
        #pragma unroll
        for (int n = 0; n < 4; n++) acc[m][n] = fz;

    const int e0 = tid, e1 = 256 + tid;
    const int r0 = e0 >> 2, c0 = ((e0 & 3) ^ (r0 & 3)) * 8;
    const int r1 = e1 >> 2, c1 = ((e1 & 3) ^ (r1 & 3)) * 8;

    for (int k0 = 0; k0 < D_MODEL; k0 += 32) {
        GLDS16(X + (size_t)(tM + r0) * D_MODEL + k0 + c0, &lsA[e0 * 8]);
        GLDS16(X + (size_t)(tM + r1) * D_MODEL + k0 + c1, &lsA[e1 * 8]);
        GLDS16(W + (size_t)(tN + r0) * D_MODEL + k0 + c0, &lsB[e0 * 8]);
        GLDS16(W + (size_t)(tN + r1) * D_MODEL + k0 + c1, &lsB[e1 * 8]);
        __syncthreads();
        bf16x8 af[4], bfr[4];
        #pragma unroll
        for (int m = 0; m < 4; m++) {
            int row = wr*64 + m*16 + lr;
            af[m] = *(const bf16x8*)&lsA[row*32 + ((lk ^ (row & 3)) * 8)];
        }
        #pragma unroll
        for (int n = 0; n < 4; n++) {
            int row = wc*64 + n*16 + lr;
            bfr[n] = *(const bf16x8*)&lsB[row*32 + ((lk ^ (row & 3)) * 8)];
        }
        #pragma unroll
        for (int m = 0; m < 4; m++)
            #pragma unroll
            for (int n = 0; n < 4; n++)
                acc[m][n] = __builtin_amdgcn_mfma_f32_16x16x32_bf16(af[m], bfr[n], acc[m][n], 0, 0, 0);
        __syncthreads();
    }
    #pragma unroll
    for (int m = 0; m < 4; m++) {
        int ibase = tM + wr*64 + m*16 + lk*4;
        #pragma unroll
        for (int n = 0; n < 4; n++) {
            int j = tN + wc*64 + n*16 + lr;
            float bj = bias[j];
            #pragma unroll
            for (int r = 0; r < 4; r++)
                Out[(size_t)(ibase + r) * D_MODEL + j] = acc[m][n][r] + bj;
        }
    }
}

// ---------------- V transpose: [bh][s][d] -> [bh][d][s] ----------------
__global__ __launch_bounds__(256) void vtrans(const unsigned short* __restrict__ V,
                                              unsigned short* __restrict__ Vt) {
    __shared__ unsigned short t[64][80];
    const int bh = blockIdx.y;
    const int s0 = blockIdx.x * 64;
    const int tid = threadIdx.x;
    #pragma unroll
    for (int i = 0; i < 2; i++) {
        int e = i*256 + tid;
        int r = e >> 3, c = e & 7;
        u16x8 v = *(const u16x8*)&V[((size_t)bh * SEQ + s0 + r) * DH + c*8];
        *(u16x8*)&t[r][c*8] = v;
    }
    __syncthreads();
    #pragma unroll
    for (int i = 0; i < 2; i++) {
        int e = i*256 + tid;
        int d = e >> 3, c = e & 7;
        u16x8 o;
        #pragma unroll
        for (int j = 0; j < 8; j++) o[j] = t[c*8 + j][d];
        *(u16x8*)&Vt[((size_t)bh * DH + d) * SEQ + s0 + c*8] = o;
    }
}

// ---------------- qer[b,h,l] = dot(Q[b,h,l,:], Er[l,:]) ----------------
__global__ __launch_bounds__(256) void qer_k(const unsigned short* __restrict__ Q,
                                             const float* __restrict__ Er,
                                             float* __restrict__ qer) {
    int gw = blockIdx.x * 4 + (threadIdx.x >> 6);
    int lane = threadIdx.x & 63;
    int l = gw & (SEQ - 1);
    float p = b2f(Q[(size_t)gw * DH + lane]) * Er[l * DH + lane];
    #pragma unroll
    for (int m = 32; m >= 1; m >>= 1) p += __shfl_xor(p, m, 64);
    if (lane == 0) qer[gw] = p;
}

// ---------------- flash attention, swapped-QK layout ----------------
// Per wave: 16 q-rows (q = w*16 + lane&15, lane-local softmax state).
// S^T = K·Q^T  (A = K rows, B = Q rows);  O^T = V^T·P^T (A = V^T rows, B = P^T cols).
__global__ __launch_bounds__(256) void attn_k(
    const unsigned short* __restrict__ Q, const unsigned short* __restrict__ Kg,
    const unsigned short* __restrict__ Vt, const float* __restrict__ qer,
    unsigned short* __restrict__ Om)
{
    __shared__ unsigned short lsK[64*64];
    __shared__ unsigned short lsV[64*64];
    __shared__ unsigned short lsP[64*80];   // [q][k] P^T, 80-elem row pad (16B-aligned rows)
    // balanced qt mapping: flip qt in dispatch-round bit (id>>8) so each CU's
    // blocks sum to ~constant work despite causal qt+1 scaling.
    const int id = blockIdx.x;
    const int xq = id & 31;
    const int mm = id >> 5;
    const int qt = (mm & 8) ? (31 - xq) : xq;
    const int bh = mm;
    const int b = bh >> 4, h = bh & 15;
    const int tid = threadIdx.x;
    const int w = tid >> 6, lane = tid & 63;
    const int lr = lane & 15, lk = lane >> 4;
    const f32x4 fz = {0.f, 0.f, 0.f, 0.f};

    const int qrow = qt*64 + w*16 + lr;
    const unsigned short* Qrow = Q + ((size_t)bh * SEQ + qrow) * DH;
    bf16x8 bq0 = *(const bf16x8*)&Qrow[lk*8];
    bf16x8 bq1 = *(const bf16x8*)&Qrow[32 + lk*8];

    f32x4 o[4];
    #pragma unroll
    for (int df = 0; df < 4; df++) o[df] = fz;
    float mrun = -3.0e38f, lsum = 0.0f;
    const float SCL = 0.125f * 1.44269504088896f;  // 1/sqrt(64) * log2(e)
    const float* qerb = qer + (size_t)bh * SEQ;

    for (int kt = 0; kt <= qt; kt++) {
        // relative-bias values for this lane's odd-k slots (r=1,3), issued
        // before the barrier so latency hides under the staging wait
        float biasv[4][2];
        #pragma unroll
        for (int kf = 0; kf < 4; kf++) {
            #pragma unroll
            for (int ri = 0; ri < 2; ri++) {
                int kg = kt*64 + kf*16 + lk*4 + 2*ri + 1;
                biasv[kf][ri] = qerb[(SEQ - 1 + kg) >> 1] * SCL;
            }
        }
        #pragma unroll
        for (int i = 0; i < 2; i++) {
            int e = i*256 + tid;
            int r = e >> 3, c = ((e & 7) ^ (r & 7)) * 8;
            GLDS16(Kg + ((size_t)bh * SEQ + kt*64 + r) * DH + c, &lsK[e * 8]);
            GLDS16(Vt + ((size_t)bh * DH + r) * SEQ + kt*64 + c, &lsV[e * 8]);
        }
        __syncthreads();
        // QK^T (swapped): st[kf][r] = S[k = kt*64+kf*16+lk*4+r][q = qrow]
        float st[4][4];
        #pragma unroll
        for (int kf = 0; kf < 4; kf++) {
            int row = kf*16 + lr;
            bf16x8 a0 = *(const bf16x8*)&lsK[row*64 + ((lk ^ (row & 7)) * 8)];
            bf16x8 a1 = *(const bf16x8*)&lsK[row*64 + (((4 + lk) ^ (row & 7)) * 8)];
            f32x4 z = fz;
            z = __builtin_amdgcn_mfma_f32_16x16x32_bf16(a0, bq0, z, 0, 0, 0);
            z = __builtin_amdgcn_mfma_f32_16x16x32_bf16(a1, bq1, z, 0, 0, 0);
            st[kf][0] = z[0] * SCL;
            st[kf][1] = z[1] * SCL + biasv[kf][0];
            st[kf][2] = z[2] * SCL;
            st[kf][3] = z[3] * SCL + biasv[kf][1];
        }
        if (kt == qt) {  // causal mask on the diagonal tile
            #pragma unroll
            for (int kf = 0; kf < 4; kf++) {
                int kg0 = kt*64 + kf*16 + lk*4;
                #pragma unroll
                for (int r = 0; r < 4; r++)
                    if (kg0 + r > qrow) st[kf][r] = -3.0e38f;
            }
        }
        // row max over this lane's 16 k + across the 4 lk groups (2 shuffles)
        float pm = st[0][0];
        #pragma unroll
        for (int kf = 0; kf < 4; kf++)
            #pragma unroll
            for (int r = 0; r < 4; r++) pm = fmaxf(pm, st[kf][r]);
        pm = fmaxf(pm, __shfl_xor(pm, 16, 64));
        pm = fmaxf(pm, __shfl_xor(pm, 32, 64));
        // deferred rescale (T13, THR=8 in log2 units -> P bounded by 256)
        if (pm > mrun + 8.0f) {
            float sc = exp2f(mrun - pm);
            mrun = pm;
            lsum *= sc;
            #pragma unroll
            for (int df = 0; df < 4; df++)
                #pragma unroll
                for (int r = 0; r < 4; r++) o[df][r] *= sc;
        }
        float p[4][4];
        float rs = 0.0f;
        #pragma unroll
        for (int kf = 0; kf < 4; kf++)
            #pragma unroll
            for (int r = 0; r < 4; r++) {
                p[kf][r] = exp2f(st[kf][r] - mrun);
                rs += p[kf][r];
            }
        rs += __shfl_xor(rs, 16, 64);
        rs += __shfl_xor(rs, 32, 64);
        lsum += rs;
        // P^T -> LDS: lane writes its 16 values as 4x 8B (k-contiguous)
        #pragma unroll
        for (int kf = 0; kf < 4; kf++) {
            union { __hip_bfloat162 h2[2]; unsigned long long u; } pk;
            pk.h2[0] = __float22bfloat162_rn(float2{p[kf][0], p[kf][1]});
            pk.h2[1] = __float22bfloat162_rn(float2{p[kf][2], p[kf][3]});
            *(unsigned long long*)&lsP[(w*16 + lr)*80 + kf*16 + lk*4] = pk.u;
        }
        bf16x8 pb0 = *(const bf16x8*)&lsP[(w*16 + lr)*80 + lk*8];
        bf16x8 pb1 = *(const bf16x8*)&lsP[(w*16 + lr)*80 + 32 + lk*8];
        // PV (swapped): o[df] accumulates O^T[d = df*16+lk*4+r][q = qrow]
        #pragma unroll
        for (int df = 0; df < 4; df++) {
            int row = df*16 + lr;
            bf16x8 v0 = *(const bf16x8*)&lsV[row*64 + ((lk ^ (row & 7)) * 8)];
            bf16x8 v1 = *(const bf16x8*)&lsV[row*64 + (((4 + lk) ^ (row & 7)) * 8)];
            o[df] = __builtin_amdgcn_mfma_f32_16x16x32_bf16(v0, pb0, o[df], 0, 0, 0);
            o[df] = __builtin_amdgcn_mfma_f32_16x16x32_bf16(v1, pb1, o[df], 0, 0, 0);
        }
        __syncthreads();
    }
    // epilogue: out[b][s = qrow][h*64 + d], d = df*16 + lk*4 + r
    float inv = 1.0f / lsum;
    #pragma unroll
    for (int df = 0; df < 4; df++) {
        ushort4 ov;
        ov.x = f2b(o[df][0] * inv);
        ov.y = f2b(o[df][1] * inv);
        ov.z = f2b(o[df][2] * inv);
        ov.w = f2b(o[df][3] * inv);
        *(ushort4*)&Om[((size_t)(b * SEQ + qrow)) * D_MODEL + h*64 + df*16 + lk*4] = ov;
    }
}

extern "C" void kernel_launch(void* const* d_in, const int* in_sizes, int n_in,
                              void* d_out, int out_size, void* d_ws, size_t ws_size,
                              hipStream_t stream) {
    const float* x  = (const float*)d_in[0];
    const float* Wq = (const float*)d_in[1];
    const float* bq = (const float*)d_in[2];
    const float* Wk = (const float*)d_in[3];
    const float* bk = (const float*)d_in[4];
    const float* Wv = (const float*)d_in[5];
    const float* bv = (const float*)d_in[6];
    const float* Wo = (const float*)d_in[7];
    const float* bo = (const float*)d_in[8];
    const float* Er = (const float*)d_in[9];

    char* ws = (char*)d_ws;
    unsigned short* xb  = (unsigned short*)(ws);                      // 8 MB; reused as attn out
    unsigned short* Wqb = (unsigned short*)(ws + 8388608);            // 2 MB
    unsigned short* Wkb = (unsigned short*)(ws + 8388608 + 2097152);
    unsigned short* Wvb = (unsigned short*)(ws + 8388608 + 2*2097152);
    unsigned short* Wob = (unsigned short*)(ws + 8388608 + 3*2097152);
    unsigned short* Qb  = (unsigned short*)(ws + 16777216);           // 8 MB
    unsigned short* Kb  = (unsigned short*)(ws + 16777216 + 8388608);
    unsigned short* Vb  = (unsigned short*)(ws + 16777216 + 2*8388608);
    unsigned short* Vtb = (unsigned short*)(ws + 16777216 + 3*8388608);
    float* qer          = (float*)(ws + 16777216 + 4*8388608);        // 256 KB

    cvt_f32_bf16<<<2048, 256, 0, stream>>>(x,  xb,  MROWS*D_MODEL/4);
    cvt_f32_bf16<<<1024, 256, 0, stream>>>(Wq, Wqb, D_MODEL*D_MODEL/4);
    cvt_f32_bf16<<<1024, 256, 0, stream>>>(Wk, Wkb, D_MODEL*D_MODEL/4);
    cvt_f32_bf16<<<1024, 256, 0, stream>>>(Wv, Wvb, D_MODEL*D_MODEL/4);
    cvt_f32_bf16<<<1024, 256, 0, stream>>>(Wo, Wob, D_MODEL*D_MODEL/4);

    gemm_qkv<<<dim3(8, 32, 3), 256, 0, stream>>>(xb, Wqb, Wkb, Wvb, bq, bk, bv, Qb, Kb, Vb);
    vtrans<<<dim3(32, 32), 256, 0, stream>>>(Vb, Vtb);
    qer_k<<<16384, 256, 0, stream>>>(Qb, Er, qer);
    attn_k<<<1024, 256, 0, stream>>>(Qb, Kb, Vtb, qer, xb);
    gemm_out<<<dim3(8, 32), 256, 0, stream>>>(xb, Wob, bo, (float*)d_out);
}

// Round 3
// 141.358 us; speedup vs baseline: 1.6810x; 1.1320x over previous
//
#include <hip/hip_runtime.h>
#include <hip/hip_bf16.h>

#define D_MODEL 1024
#define NHEAD 16
#define DH 64
#define BSZ 2
#define SEQ 2048
#define MROWS (BSZ*SEQ)

typedef __attribute__((ext_vector_type(4))) float f32x4;
typedef __attribute__((ext_vector_type(8))) __bf16 bf16x8;
typedef __attribute__((ext_vector_type(8))) unsigned short u16x8;

__device__ __forceinline__ float b2f(unsigned short u) {
    union { unsigned int i; float f; } v; v.i = ((unsigned int)u) << 16; return v.f;
}
__device__ __forceinline__ unsigned short f2b(float f) {
    union { float f; unsigned int i; } v; v.f = f;
    unsigned int u = v.i;
    u += 0x7fffu + ((u >> 16) & 1u);
    return (unsigned short)(u >> 16);
}

#define GLDS16(gptr, lptr) \
    __builtin_amdgcn_global_load_lds((__attribute__((address_space(1))) void*)(gptr), \
                                     (__attribute__((address_space(3))) void*)(lptr), 16, 0, 0)

// ---------------- f32 -> bf16 convert (single) ----------------
__global__ __launch_bounds__(256) void cvt_f32_bf16(const float* __restrict__ src,
                                                    unsigned short* __restrict__ dst, int n4) {
    int i = blockIdx.x * 256 + threadIdx.x;
    int stride = gridDim.x * 256;
    for (; i < n4; i += stride) {
        float4 v = ((const float4*)src)[i];
        ushort4 o;
        o.x = f2b(v.x); o.y = f2b(v.y); o.z = f2b(v.z); o.w = f2b(v.w);
        ((ushort4*)dst)[i] = o;
    }
}

// ---------------- f32 -> bf16 convert (4 weight matrices in one launch) ----------------
__global__ __launch_bounds__(256) void cvt4_f32_bf16(
    const float* __restrict__ s0, const float* __restrict__ s1,
    const float* __restrict__ s2, const float* __restrict__ s3,
    unsigned short* __restrict__ d0, unsigned short* __restrict__ d1,
    unsigned short* __restrict__ d2, unsigned short* __restrict__ d3, int n4) {
    const int seg = blockIdx.y;
    const float* src = (seg==0) ? s0 : (seg==1) ? s1 : (seg==2) ? s2 : s3;
    unsigned short* dst = (seg==0) ? d0 : (seg==1) ? d1 : (seg==2) ? d2 : d3;
    int i = blockIdx.x * 256 + threadIdx.x;
    int stride = gridDim.x * 256;
    for (; i < n4; i += stride) {
        float4 v = ((const float4*)src)[i];
        ushort4 o;
        o.x = f2b(v.x); o.y = f2b(v.y); o.z = f2b(v.z); o.w = f2b(v.w);
        ((ushort4*)dst)[i] = o;
    }
}

// ---------------- QKV GEMM: out = x @ W^T + b, head-split bf16 output, dbuf ----------------
__global__ __launch_bounds__(256) void gemm_qkv(
    const unsigned short* __restrict__ X,
    const unsigned short* __restrict__ Wq, const unsigned short* __restrict__ Wk,
    const unsigned short* __restrict__ Wv,
    const float* __restrict__ bq, const float* __restrict__ bk, const float* __restrict__ bv,
    unsigned short* __restrict__ Qo, unsigned short* __restrict__ Ko, unsigned short* __restrict__ Vo)
{
    __shared__ unsigned short lsA[2][128*32];
    __shared__ unsigned short lsB[2][128*32];
    const int tid = threadIdx.x;
    const int z = blockIdx.z;
    const unsigned short* W = (z==0) ? Wq : (z==1) ? Wk : Wv;
    const float* bias = (z==0) ? bq : (z==1) ? bk : bv;
    unsigned short* Out = (z==0) ? Qo : (z==1) ? Ko : Vo;
    const int tM = blockIdx.y * 128;
    const int tN = blockIdx.x * 128;
    const int w = tid >> 6, lane = tid & 63;
    const int wr = w >> 1, wc = w & 1;
    const int lr = lane & 15, lk = lane >> 4;
    const f32x4 fz = {0.f, 0.f, 0.f, 0.f};
    f32x4 acc[4][4];
    #pragma unroll
    for (int m = 0; m < 4; m++)
        #pragma unroll
        for (int n = 0; n < 4; n++) acc[m][n] = fz;

    const int e0 = tid, e1 = 256 + tid;
    const int r0 = e0 >> 2, c0 = ((e0 & 3) ^ (r0 & 3)) * 8;
    const int r1 = e1 >> 2, c1 = ((e1 & 3) ^ (r1 & 3)) * 8;

#define GEMM_STAGE(buf, k0_) do { \
        GLDS16(X + (size_t)(tM + r0) * D_MODEL + (k0_) + c0, &lsA[buf][e0 * 8]); \
        GLDS16(X + (size_t)(tM + r1) * D_MODEL + (k0_) + c1, &lsA[buf][e1 * 8]); \
        GLDS16(W + (size_t)(tN + r0) * D_MODEL + (k0_) + c0, &lsB[buf][e0 * 8]); \
        GLDS16(W + (size_t)(tN + r1) * D_MODEL + (k0_) + c1, &lsB[buf][e1 * 8]); \
    } while (0)

    GEMM_STAGE(0, 0);
    __syncthreads();
    int cur = 0;
    for (int k0 = 0; k0 < D_MODEL; k0 += 32) {
        if (k0 + 32 < D_MODEL) GEMM_STAGE(cur ^ 1, k0 + 32);
        bf16x8 af[4], bfr[4];
        #pragma unroll
        for (int m = 0; m < 4; m++) {
            int row = wr*64 + m*16 + lr;
            af[m] = *(const bf16x8*)&lsA[cur][row*32 + ((lk ^ (row & 3)) * 8)];
        }
        #pragma unroll
        for (int n = 0; n < 4; n++) {
            int row = wc*64 + n*16 + lr;
            bfr[n] = *(const bf16x8*)&lsB[cur][row*32 + ((lk ^ (row & 3)) * 8)];
        }
        #pragma unroll
        for (int m = 0; m < 4; m++)
            #pragma unroll
            for (int n = 0; n < 4; n++)
                acc[m][n] = __builtin_amdgcn_mfma_f32_16x16x32_bf16(af[m], bfr[n], acc[m][n], 0, 0, 0);
        __syncthreads();
        cur ^= 1;
    }
    #pragma unroll
    for (int m = 0; m < 4; m++) {
        int ibase = tM + wr*64 + m*16 + lk*4;
        #pragma unroll
        for (int n = 0; n < 4; n++) {
            int j = tN + wc*64 + n*16 + lr;
            float bj = bias[j];
            int h = j >> 6, d = j & 63;
            #pragma unroll
            for (int r = 0; r < 4; r++) {
                int row = ibase + r;
                int b = row >> 11, s = row & 2047;
                Out[((size_t)(b*NHEAD + h) * SEQ + s) * DH + d] = f2b(acc[m][n][r] + bj);
            }
        }
    }
}

// ---------------- Output GEMM: out = A @ W^T + b, f32 output, dbuf ----------------
__global__ __launch_bounds__(256) void gemm_out(
    const unsigned short* __restrict__ X, const unsigned short* __restrict__ W,
    const float* __restrict__ bias, float* __restrict__ Out)
{
    __shared__ unsigned short lsA[2][128*32];
    __shared__ unsigned short lsB[2][128*32];
    const int tid = threadIdx.x;
    const int tM = blockIdx.y * 128;
    const int tN = blockIdx.x * 128;
    const int w = tid >> 6, lane = tid & 63;
    const int wr = w >> 1, wc = w & 1;
    const int lr = lane & 15, lk = lane >> 4;
    const f32x4 fz = {0.f, 0.f, 0.f, 0.f};
    f32x4 acc[4][4];
    #pragma unroll
    for (int m = 0; m < 4; m++)
        #pragma unroll
        for (int n = 0; n < 4; n++) acc[m][n] = fz;

    const int e0 = tid, e1 = 256 + tid;
    const int r0 = e0 >> 2, c0 = ((e0 & 3) ^ (r0 & 3)) * 8;
    const int r1 = e1 >> 2, c1 = ((e1 & 3) ^ (r1 & 3)) * 8;

    GEMM_STAGE(0, 0);
    __syncthreads();
    int cur = 0;
    for (int k0 = 0; k0 < D_MODEL; k0 += 32) {
        if (k0 + 32 < D_MODEL) GEMM_STAGE(cur ^ 1, k0 + 32);
        bf16x8 af[4], bfr[4];
        #pragma unroll
        for (int m = 0; m < 4; m++) {
            int row = wr*64 + m*16 + lr;
            af[m] = *(const bf16x8*)&lsA[cur][row*32 + ((lk ^ (row & 3)) * 8)];
        }
        #pragma unroll
        for (int n = 0; n < 4; n++) {
            int row = wc*64 + n*16 + lr;
            bfr[n] = *(const bf16x8*)&lsB[cur][row*32 + ((lk ^ (row & 3)) * 8)];
        }
        #pragma unroll
        for (int m = 0; m < 4; m++)
            #pragma unroll
            for (int n = 0; n < 4; n++)
                acc[m][n] = __builtin_amdgcn_mfma_f32_16x16x32_bf16(af[m], bfr[n], acc[m][n], 0, 0, 0);
        __syncthreads();
        cur ^= 1;
    }
    #pragma unroll
    for (int m = 0; m < 4; m++) {
        int ibase = tM + wr*64 + m*16 + lk*4;
        #pragma unroll
        for (int n = 0; n < 4; n++) {
            int j = tN + wc*64 + n*16 + lr;
            float bj = bias[j];
            #pragma unroll
            for (int r = 0; r < 4; r++)
                Out[(size_t)(ibase + r) * D_MODEL + j] = acc[m][n][r] + bj;
        }
    }
}

// ---------------- V transpose: [bh][s][d] -> [bh][d][s] ----------------
__global__ __launch_bounds__(256) void vtrans(const unsigned short* __restrict__ V,
                                              unsigned short* __restrict__ Vt) {
    __shared__ unsigned short t[64][80];
    const int bh = blockIdx.y;
    const int s0 = blockIdx.x * 64;
    const int tid = threadIdx.x;
    #pragma unroll
    for (int i = 0; i < 2; i++) {
        int e = i*256 + tid;
        int r = e >> 3, c = e & 7;
        u16x8 v = *(const u16x8*)&V[((size_t)bh * SEQ + s0 + r) * DH + c*8];
        *(u16x8*)&t[r][c*8] = v;
    }
    __syncthreads();
    #pragma unroll
    for (int i = 0; i < 2; i++) {
        int e = i*256 + tid;
        int d = e >> 3, c = e & 7;
        u16x8 o;
        #pragma unroll
        for (int j = 0; j < 8; j++) o[j] = t[c*8 + j][d];
        *(u16x8*)&Vt[((size_t)bh * DH + d) * SEQ + s0 + c*8] = o;
    }
}

// ---------------- qer[b,h,l] = dot(Q[b,h,l,:], Er[l,:]) ----------------
__global__ __launch_bounds__(256) void qer_k(const unsigned short* __restrict__ Q,
                                             const float* __restrict__ Er,
                                             float* __restrict__ qer) {
    int gw = blockIdx.x * 4 + (threadIdx.x >> 6);
    int lane = threadIdx.x & 63;
    int l = gw & (SEQ - 1);
    float p = b2f(Q[(size_t)gw * DH + lane]) * Er[l * DH + lane];
    #pragma unroll
    for (int m = 32; m >= 1; m >>= 1) p += __shfl_xor(p, m, 64);
    if (lane == 0) qer[gw] = p;
}

// ---------------- flash attention, swapped-QK layout, double-buffered K/V ----------------
// Per wave: 16 q-rows (q = w*16 + lane&15, lane-local softmax state).
// S^T = K·Q^T  (A = K rows, B = Q rows);  O^T = V^T·P^T (A = V^T rows, B = P^T cols).
__global__ __launch_bounds__(256) void attn_k(
    const unsigned short* __restrict__ Q, const unsigned short* __restrict__ Kg,
    const unsigned short* __restrict__ Vt, const float* __restrict__ qer,
    unsigned short* __restrict__ Om)
{
    __shared__ unsigned short lsK[2][64*64];
    __shared__ unsigned short lsV[2][64*64];
    __shared__ unsigned short lsP[64*64];   // [q][k] P^T, chunk-XOR swizzled
    // balanced qt mapping: flip qt in dispatch-round bit so each CU's
    // blocks sum to ~constant work despite causal qt+1 scaling.
    const int id = blockIdx.x;
    const int xq = id & 31;
    const int mm = id >> 5;
    const int qt = (mm & 8) ? (31 - xq) : xq;
    const int bh = mm;
    const int b = bh >> 4, h = bh & 15;
    const int tid = threadIdx.x;
    const int w = tid >> 6, lane = tid & 63;
    const int lr = lane & 15, lk = lane >> 4;
    const int q = w*16 + lr;
    const f32x4 fz = {0.f, 0.f, 0.f, 0.f};

    const int qrow = qt*64 + q;
    const unsigned short* Qrow = Q + ((size_t)bh * SEQ + qrow) * DH;
    bf16x8 bq0 = *(const bf16x8*)&Qrow[lk*8];
    bf16x8 bq1 = *(const bf16x8*)&Qrow[32 + lk*8];

    f32x4 o[4];
    #pragma unroll
    for (int df = 0; df < 4; df++) o[df] = fz;
    float mrun = -3.0e38f, lsum = 0.0f;
    const float SCL = 0.125f * 1.44269504088896f;  // 1/sqrt(64) * log2(e)
    const float* qerb = qer + (size_t)bh * SEQ;

#define ATTN_STAGE(buf, kt_) do { \
        _Pragma("unroll") \
        for (int i = 0; i < 2; i++) { \
            int e = i*256 + tid; \
            int r = e >> 3, c = ((e & 7) ^ (r & 7)) * 8; \
            GLDS16(Kg + ((size_t)bh * SEQ + (kt_)*64 + r) * DH + c, &lsK[buf][e * 8]); \
            GLDS16(Vt + ((size_t)bh * DH + r) * SEQ + (kt_)*64 + c, &lsV[buf][e * 8]); \
        } \
    } while (0)

    ATTN_STAGE(0, 0);
    __syncthreads();
    int cur = 0;

    for (int kt = 0; kt <= qt; kt++) {
        if (kt < qt) ATTN_STAGE(cur ^ 1, kt + 1);   // prefetch next tile; vmcnt drains at barrier
        // relative-bias values for this lane's odd-k slots (r=1,3)
        float biasv[4][2];
        #pragma unroll
        for (int kf = 0; kf < 4; kf++) {
            #pragma unroll
            for (int ri = 0; ri < 2; ri++) {
                int kg = kt*64 + kf*16 + lk*4 + 2*ri + 1;
                biasv[kf][ri] = qerb[(SEQ - 1 + kg) >> 1] * SCL;
            }
        }
        // QK^T (swapped): st[kf][r] = S[k = kt*64+kf*16+lk*4+r][q = qrow]
        float st[4][4];
        __builtin_amdgcn_s_setprio(1);
        #pragma unroll
        for (int kf = 0; kf < 4; kf++) {
            int row = kf*16 + lr;
            bf16x8 a0 = *(const bf16x8*)&lsK[cur][row*64 + ((lk ^ (row & 7)) * 8)];
            bf16x8 a1 = *(const bf16x8*)&lsK[cur][row*64 + (((4 + lk) ^ (row & 7)) * 8)];
            f32x4 zv = fz;
            zv = __builtin_amdgcn_mfma_f32_16x16x32_bf16(a0, bq0, zv, 0, 0, 0);
            zv = __builtin_amdgcn_mfma_f32_16x16x32_bf16(a1, bq1, zv, 0, 0, 0);
            st[kf][0] = zv[0] * SCL;
            st[kf][1] = zv[1] * SCL + biasv[kf][0];
            st[kf][2] = zv[2] * SCL;
            st[kf][3] = zv[3] * SCL + biasv[kf][1];
        }
        __builtin_amdgcn_s_setprio(0);
        if (kt == qt) {  // causal mask on the diagonal tile
            #pragma unroll
            for (int kf = 0; kf < 4; kf++) {
                int kg0 = kt*64 + kf*16 + lk*4;
                #pragma unroll
                for (int r = 0; r < 4; r++)
                    if (kg0 + r > qrow) st[kf][r] = -3.0e38f;
            }
        }
        // row max: 15 lane-local fmax + 2 shuffles
        float pm = st[0][0];
        #pragma unroll
        for (int kf = 0; kf < 4; kf++)
            #pragma unroll
            for (int r = 0; r < 4; r++) pm = fmaxf(pm, st[kf][r]);
        pm = fmaxf(pm, __shfl_xor(pm, 16, 64));
        pm = fmaxf(pm, __shfl_xor(pm, 32, 64));
        // deferred rescale (T13, THR=8 in log2 units -> P bounded by 256)
        if (pm > mrun + 8.0f) {
            float sc = exp2f(mrun - pm);
            mrun = pm;
            lsum *= sc;
            #pragma unroll
            for (int df = 0; df < 4; df++)
                #pragma unroll
                for (int r = 0; r < 4; r++) o[df][r] *= sc;
        }
        float p[4][4];
        float rs = 0.0f;
        #pragma unroll
        for (int kf = 0; kf < 4; kf++)
            #pragma unroll
            for (int r = 0; r < 4; r++) {
                p[kf][r] = exp2f(st[kf][r] - mrun);
                rs += p[kf][r];
            }
        rs += __shfl_xor(rs, 16, 64);
        rs += __shfl_xor(rs, 32, 64);
        lsum += rs;
        // P^T -> LDS, chunk-XOR swizzle (order-preserving for b128 reads)
        #pragma unroll
        for (int kf = 0; kf < 4; kf++) {
            union { __hip_bfloat162 h2[2]; unsigned long long u; } pk;
            pk.h2[0] = __float22bfloat162_rn(float2{p[kf][0], p[kf][1]});
            pk.h2[1] = __float22bfloat162_rn(float2{p[kf][2], p[kf][3]});
            *(unsigned long long*)&lsP[q*64 + ((((kf<<2)|lk) ^ ((lr&7)<<1))<<2)] = pk.u;
        }
        bf16x8 pb0 = *(const bf16x8*)&lsP[q*64 + ((lk ^ (lr&7))<<3)];
        bf16x8 pb1 = *(const bf16x8*)&lsP[q*64 + (((4+lk) ^ (lr&7))<<3)];
        // PV (swapped): o[df] accumulates O^T[d = df*16+lk*4+r][q = qrow]
        __builtin_amdgcn_s_setprio(1);
        #pragma unroll
        for (int df = 0; df < 4; df++) {
            int row = df*16 + lr;
            bf16x8 v0 = *(const bf16x8*)&lsV[cur][row*64 + ((lk ^ (row & 7)) * 8)];
            bf16x8 v1 = *(const bf16x8*)&lsV[cur][row*64 + (((4 + lk) ^ (row & 7)) * 8)];
            o[df] = __builtin_amdgcn_mfma_f32_16x16x32_bf16(v0, pb0, o[df], 0, 0, 0);
            o[df] = __builtin_amdgcn_mfma_f32_16x16x32_bf16(v1, pb1, o[df], 0, 0, 0);
        }
        __builtin_amdgcn_s_setprio(0);
        __syncthreads();
        cur ^= 1;
    }
    // epilogue: out[b][s = qrow][h*64 + d], d = df*16 + lk*4 + r
    float inv = 1.0f / lsum;
    #pragma unroll
    for (int df = 0; df < 4; df++) {
        ushort4 ov;
        ov.x = f2b(o[df][0] * inv);
        ov.y = f2b(o[df][1] * inv);
        ov.z = f2b(o[df][2] * inv);
        ov.w = f2b(o[df][3] * inv);
        *(ushort4*)&Om[((size_t)(b * SEQ + qrow)) * D_MODEL + h*64 + df*16 + lk*4] = ov;
    }
}

extern "C" void kernel_launch(void* const* d_in, const int* in_sizes, int n_in,
                              void* d_out, int out_size, void* d_ws, size_t ws_size,
                              hipStream_t stream) {
    const float* x  = (const float*)d_in[0];
    const float* Wq = (const float*)d_in[1];
    const float* bq = (const float*)d_in[2];
    const float* Wk = (const float*)d_in[3];
    const float* bk = (const float*)d_in[4];
    const float* Wv = (const float*)d_in[5];
    const float* bv = (const float*)d_in[6];
    const float* Wo = (const float*)d_in[7];
    const float* bo = (const float*)d_in[8];
    const float* Er = (const float*)d_in[9];

    char* ws = (char*)d_ws;
    unsigned short* xb  = (unsigned short*)(ws);                      // 8 MB; reused as attn out
    unsigned short* Wqb = (unsigned short*)(ws + 8388608);            // 2 MB
    unsigned short* Wkb = (unsigned short*)(ws + 8388608 + 2097152);
    unsigned short* Wvb = (unsigned short*)(ws + 8388608 + 2*2097152);
    unsigned short* Wob = (unsigned short*)(ws + 8388608 + 3*2097152);
    unsigned short* Qb  = (unsigned short*)(ws + 16777216);           // 8 MB
    unsigned short* Kb  = (unsigned short*)(ws + 16777216 + 8388608);
    unsigned short* Vb  = (unsigned short*)(ws + 16777216 + 2*8388608);
    unsigned short* Vtb = (unsigned short*)(ws + 16777216 + 3*8388608);
    float* qer          = (float*)(ws + 16777216 + 4*8388608);        // 256 KB

    cvt_f32_bf16<<<2048, 256, 0, stream>>>(x, xb, MROWS*D_MODEL/4);
    cvt4_f32_bf16<<<dim3(256, 4), 256, 0, stream>>>(Wq, Wk, Wv, Wo, Wqb, Wkb, Wvb, Wob,
                                                    D_MODEL*D_MODEL/4);

    gemm_qkv<<<dim3(8, 32, 3), 256, 0, stream>>>(xb, Wqb, Wkb, Wvb, bq, bk, bv, Qb, Kb, Vb);
    vtrans<<<dim3(32, 32), 256, 0, stream>>>(Vb, Vtb);
    qer_k<<<16384, 256, 0, stream>>>(Qb, Er, qer);
    attn_k<<<1024, 256, 0, stream>>>(Qb, Kb, Vtb, qer, xb);
    gemm_out<<<dim3(8, 32), 256, 0, stream>>>(xb, Wob, bo, (float*)d_out);
}